// Round 13
// baseline (2037.451 us; speedup 1.0000x reference)
//
#include <hip/hip_runtime.h>
#include <hip/hip_bf16.h>

typedef unsigned short u16;
typedef __attribute__((ext_vector_type(8))) short bf16x8;
typedef __attribute__((ext_vector_type(4))) short bf16x4;
typedef __attribute__((ext_vector_type(4))) float floatx4;
typedef __attribute__((ext_vector_type(4))) unsigned short u16x4;

__device__ __forceinline__ float b2f(u16 u) {
  unsigned int i = ((unsigned int)u) << 16;
  return __builtin_bit_cast(float, i);
}
__device__ __forceinline__ u16 f2b(float f) {
  __hip_bfloat16 h = __float2bfloat16(f);
  return __builtin_bit_cast(u16, h);
}
#define MFMA16(a, b, c) __builtin_amdgcn_mfma_f32_16x16x32_bf16((a), (b), (c), 0, 0, 0)
#define LGKM0() __asm__ volatile("s_waitcnt lgkmcnt(0)" ::: "memory")

#if __has_builtin(__builtin_amdgcn_mfma_f32_16x16x16bf16_1k)
#define HAVE_MFMA_K16 1
#define MFMA16K16(a, b, c) __builtin_amdgcn_mfma_f32_16x16x16bf16_1k((a), (b), (c), 0, 0, 0)
#else
#define HAVE_MFMA_K16 0
#endif

// ---------------------------------------------------------------------------
// Kernel 0: fp32 -> bf16 conversion of ALL FOUR weight arrays in ONE launch.
// ---------------------------------------------------------------------------
__global__ __launch_bounds__(256) void cvt_all_kernel(
    const float* __restrict__ a1, u16* __restrict__ o1,
    const float* __restrict__ a2, u16* __restrict__ o2,
    const float* __restrict__ a3, u16* __restrict__ o3,
    const float* __restrict__ a4, u16* __restrict__ o4) {
  int b = blockIdx.x;
  const float* a; u16* o; int i; int n4;
  if (b < 768)       { a = a1; o = o1; i = b * 256 + threadIdx.x;          n4 = 196608; }
  else if (b < 1536) { a = a2; o = o2; i = (b - 768) * 256 + threadIdx.x;  n4 = 196608; }
  else if (b < 1548) { a = a3; o = o3; i = (b - 1536) * 256 + threadIdx.x; n4 = 3072; }
  else               { a = a4; o = o4; i = (b - 1548) * 256 + threadIdx.x; n4 = 3072; }
  if (i < n4) {
    float4 v = ((const float4*)a)[i];
    u16x4 r;
    r.x = f2b(v.x); r.y = f2b(v.y); r.z = f2b(v.z); r.w = f2b(v.w);
    ((u16x4*)o)[i] = r;
  }
}

// ---------------------------------------------------------------------------
// Kernel A: LayerNorm (shared mu/rsigma) + pos add -> both branch layouts, bf16
// ---------------------------------------------------------------------------
__global__ __launch_bounds__(256) void ln_pos_kernel(
    const float* __restrict__ x, const float* __restrict__ n3w, const float* __restrict__ n3b,
    const float* __restrict__ n4w, const float* __restrict__ n4b,
    const float* __restrict__ pos1, const float* __restrict__ pos2,
    u16* __restrict__ yW, u16* __restrict__ yH) {
  int wv = threadIdx.x >> 6, lane = threadIdx.x & 63;
  int token = blockIdx.x * 4 + wv;
  int b = token >> 12, r = (token >> 6) & 63, c = token & 63;
  const float4* xr = (const float4*)(x + (size_t)token * 512) + lane * 2;
  float4 x0 = xr[0], x1 = xr[1];
  float v[8] = {x0.x, x0.y, x0.z, x0.w, x1.x, x1.y, x1.z, x1.w};
  float s = 0.f, ss = 0.f;
#pragma unroll
  for (int j = 0; j < 8; j++) { s += v[j]; ss += v[j] * v[j]; }
#pragma unroll
  for (int off = 1; off < 64; off <<= 1) { s += __shfl_xor(s, off); ss += __shfl_xor(ss, off); }
  float mu = s * (1.0f / 512.0f);
  float var = ss * (1.0f / 512.0f) - mu * mu;
  float rs = rsqrtf(var + 1e-5f);
  int ch0 = lane * 8;
  float w3[8], b3[8], w4[8], b4[8], p1[8], p2[8];
  *(float4*)&w3[0] = *(const float4*)(n3w + ch0); *(float4*)&w3[4] = *(const float4*)(n3w + ch0 + 4);
  *(float4*)&b3[0] = *(const float4*)(n3b + ch0); *(float4*)&b3[4] = *(const float4*)(n3b + ch0 + 4);
  *(float4*)&w4[0] = *(const float4*)(n4w + ch0); *(float4*)&w4[4] = *(const float4*)(n4w + ch0 + 4);
  *(float4*)&b4[0] = *(const float4*)(n4b + ch0); *(float4*)&b4[4] = *(const float4*)(n4b + ch0 + 4);
  const float* p1p = pos1 + (size_t)c * 512 + ch0;
  const float* p2p = pos2 + (size_t)r * 512 + ch0;
  *(float4*)&p1[0] = *(const float4*)p1p; *(float4*)&p1[4] = *(const float4*)(p1p + 4);
  *(float4*)&p2[0] = *(const float4*)p2p; *(float4*)&p2[4] = *(const float4*)(p2p + 4);
  bf16x8 ow, oh;
#pragma unroll
  for (int j = 0; j < 8; j++) {
    float xn = (v[j] - mu) * rs;
    ow[j] = (short)f2b(xn * w3[j] + b3[j] + p1[j]);
    oh[j] = (short)f2b(xn * w4[j] + b4[j] + p2[j]);
  }
  *(bf16x8*)(yW + (size_t)token * 512 + ch0) = ow;
  size_t hrow = (size_t)b * 4096 + (size_t)c * 64 + r;
  *(bf16x8*)(yH + hrow * 512 + ch0) = oh;
}

// ---------------------------------------------------------------------------
// Shared attention core, SWAPPED layout (proven): S^T = mfma(K, Q);
// softmax: max over RAW scores, exp via fma(s,0.125,-m*0.125); PV via 16
// K=16 MFMAs straight from registers.
// ---------------------------------------------------------------------------
__device__ __forceinline__ void attn_core(bf16x8 aq0, bf16x8 aq1,
                                          const u16 (*Ks)[72], const u16 (*Vt)[72],
                                          u16 (*Psw)[72], int lane, floatx4 o[4]) {
  int ml = lane & 15, quad = lane >> 4;
  floatx4 s[4];
#pragma unroll
  for (int nt = 0; nt < 4; nt++) {
    floatx4 z = (floatx4){0.f, 0.f, 0.f, 0.f};
    bf16x8 k0 = *(const bf16x8*)&Ks[nt * 16 + ml][quad * 8];
    bf16x8 k1 = *(const bf16x8*)&Ks[nt * 16 + ml][32 + quad * 8];
    z = MFMA16(k0, aq0, z);          // swapped operands: D = S^T
    z = MFMA16(k1, aq1, z);
    s[nt] = z;
  }
  float m = -1e30f;
#pragma unroll
  for (int nt = 0; nt < 4; nt++)
#pragma unroll
    for (int r = 0; r < 4; r++) m = fmaxf(m, s[nt][r]);
  m = fmaxf(m, __shfl_xor(m, 16));
  m = fmaxf(m, __shfl_xor(m, 32));
  float mh = -m * 0.125f;
  float su = 0.f;
#pragma unroll
  for (int nt = 0; nt < 4; nt++)
#pragma unroll
    for (int r = 0; r < 4; r++) {
      float p = __expf(__builtin_fmaf(s[nt][r], 0.125f, mh));
      s[nt][r] = p; su += p;
    }
  su += __shfl_xor(su, 16);
  su += __shfl_xor(su, 32);
  float inv = 1.0f / su;
#if HAVE_MFMA_K16
  bf16x4 pa[4];
#pragma unroll
  for (int nt = 0; nt < 4; nt++)
#pragma unroll
    for (int r = 0; r < 4; r++) pa[nt][r] = (short)f2b(s[nt][r] * inv);
#pragma unroll
  for (int et = 0; et < 4; et++) {
    floatx4 z = (floatx4){0.f, 0.f, 0.f, 0.f};
#pragma unroll
    for (int nt = 0; nt < 4; nt++) {
      bf16x4 bv = *(const bf16x4*)&Vt[et * 16 + ml][nt * 16 + quad * 4];
      z = MFMA16K16(pa[nt], bv, z);
    }
    o[et] = z;
  }
#else
#pragma unroll
  for (int nt = 0; nt < 4; nt++)
#pragma unroll
    for (int r = 0; r < 4; r++)
      Psw[ml][nt * 16 + quad * 4 + r] = f2b(s[nt][r] * inv);
  LGKM0();
  bf16x8 ap0 = *(const bf16x8*)&Psw[ml][quad * 8];
  bf16x8 ap1 = *(const bf16x8*)&Psw[ml][32 + quad * 8];
#pragma unroll
  for (int et = 0; et < 4; et++) {
    floatx4 z = (floatx4){0.f, 0.f, 0.f, 0.f};
    bf16x8 b0 = *(const bf16x8*)&Vt[et * 16 + ml][quad * 8];
    bf16x8 b1 = *(const bf16x8*)&Vt[et * 16 + ml][32 + quad * 8];
    z = MFMA16(ap0, b0, z);
    z = MFMA16(ap1, b1, z);
    o[et] = z;
  }
#endif
}

// ---------------------------------------------------------------------------
// GEMM-512 phase: per (window, head, branch) compute q/k/v = y_win @ Wh^T
// (64x192, K=512) -- structurally head_qkv with K scaled 64->512 and A
// streamed from global y (L2-hot). fp32 acc over full K, single bf16 round
// (bit-identical to the old Z path). Outputs:
//   q -> per-wave Ps round-trip -> B-fragment regs (aq0, aq1)
//   k -> Ks rows [token][dim] (wave-own rows)
//   v -> Vt [dim][token] (wave-own columns)
// Wq = weight base + h*64*512; k rows at +262144, v rows at +524288.
// ---------------------------------------------------------------------------
__device__ __forceinline__ void gemm_qkv512(
    const u16* __restrict__ yrow,       // y + (w*64 + wv*16)*512
    const u16* __restrict__ Wq,
    u16 (*Ks)[72], u16 (*Vt)[72], u16 (*Ps)[72],
    int wv, int lane, bf16x8& aq0, bf16x8& aq1) {
  int ml = lane & 15, quad = lane >> 4;
  const u16* ya = yrow + (size_t)ml * 512 + quad * 8;
  bf16x8 a[16];
#pragma unroll
  for (int kk = 0; kk < 16; kk++) a[kk] = *(const bf16x8*)(ya + kk * 32);
  // ---- q group (W rows 0..63 of head slice) -> Ps round-trip -> regs ----
  {
    floatx4 acc[4];
#pragma unroll
    for (int ct = 0; ct < 4; ct++) acc[ct] = (floatx4){0.f, 0.f, 0.f, 0.f};
#pragma unroll
    for (int ct = 0; ct < 4; ct++) {
      const u16* wr = Wq + (size_t)(ct * 16 + ml) * 512 + quad * 8;
#pragma unroll
      for (int kk = 0; kk < 16; kk++) {
        bf16x8 b = *(const bf16x8*)(wr + kk * 32);
        acc[ct] = MFMA16(a[kk], b, acc[ct]);
      }
    }
#pragma unroll
    for (int ct = 0; ct < 4; ct++)
#pragma unroll
      for (int r = 0; r < 4; r++)
        Ps[quad * 4 + r][ct * 16 + ml] = f2b(acc[ct][r]);
    LGKM0();
    aq0 = *(const bf16x8*)&Ps[ml][quad * 8];
    aq1 = *(const bf16x8*)&Ps[ml][32 + quad * 8];
    LGKM0();
    __builtin_amdgcn_sched_barrier(0);
  }
  // ---- k group (W rows +512) -> Ks rows of this wave ----
  {
    floatx4 acc[4];
#pragma unroll
    for (int ct = 0; ct < 4; ct++) acc[ct] = (floatx4){0.f, 0.f, 0.f, 0.f};
#pragma unroll
    for (int ct = 0; ct < 4; ct++) {
      const u16* wr = Wq + 262144 + (size_t)(ct * 16 + ml) * 512 + quad * 8;
#pragma unroll
      for (int kk = 0; kk < 16; kk++) {
        bf16x8 b = *(const bf16x8*)(wr + kk * 32);
        acc[ct] = MFMA16(a[kk], b, acc[ct]);
      }
    }
#pragma unroll
    for (int ct = 0; ct < 4; ct++)
#pragma unroll
      for (int r = 0; r < 4; r++)
        Ks[wv * 16 + quad * 4 + r][ct * 16 + ml] = f2b(acc[ct][r]);
  }
  // ---- v group (W rows +1024) -> Vt transposed, this wave's 16 columns ----
  {
    floatx4 acc[4];
#pragma unroll
    for (int ct = 0; ct < 4; ct++) acc[ct] = (floatx4){0.f, 0.f, 0.f, 0.f};
#pragma unroll
    for (int ct = 0; ct < 4; ct++) {
      const u16* wr = Wq + 524288 + (size_t)(ct * 16 + ml) * 512 + quad * 8;
#pragma unroll
      for (int kk = 0; kk < 16; kk++) {
        bf16x8 b = *(const bf16x8*)(wr + kk * 32);
        acc[ct] = MFMA16(a[kk], b, acc[ct]);
      }
    }
#pragma unroll
    for (int ct = 0; ct < 4; ct++)
#pragma unroll
      for (int r = 0; r < 4; r++)
        Vt[ct * 16 + ml][wv * 16 + quad * 4 + r] = f2b(acc[ct][r]);
  }
}

// ---------------------------------------------------------------------------
// head-QKV (proven): x = o + pos via per-wave Ps round-trip, then
// x @ lw^T (64x192): k' -> Ks rows, v' -> Vt cols, q' -> Ps round-trip.
// ---------------------------------------------------------------------------
__device__ __forceinline__ void head_qkv(const floatx4 o[4], const float* pp,
                                         const u16* lw, u16 (*Ks)[72], u16 (*Vt)[72],
                                         u16 (*Ps)[72], int wv, int lane,
                                         bf16x8& axq0, bf16x8& axq1) {
  int ml = lane & 15, quad = lane >> 4;
#pragma unroll
  for (int et = 0; et < 4; et++)
#pragma unroll
    for (int r = 0; r < 4; r++) {
      int qp = wv * 16 + quad * 4 + r, e = et * 16 + ml;
      Ps[quad * 4 + r][et * 16 + ml] = f2b(o[et][r] + pp[(size_t)qp * 64 + e]);
    }
  LGKM0();
  bf16x8 ax0 = *(const bf16x8*)&Ps[ml][quad * 8];
  bf16x8 ax1 = *(const bf16x8*)&Ps[ml][32 + quad * 8];
  LGKM0();
  __builtin_amdgcn_sched_barrier(0);
#pragma unroll
  for (int nj = 0; nj < 4; nj++) {
    int col = 64 + nj * 16 + ml;
    bf16x8 b0 = *(const bf16x8*)(lw + (size_t)col * 64 + quad * 8);
    bf16x8 b1 = *(const bf16x8*)(lw + (size_t)col * 64 + 32 + quad * 8);
    floatx4 z = (floatx4){0.f, 0.f, 0.f, 0.f};
    z = MFMA16(ax0, b0, z);
    z = MFMA16(ax1, b1, z);
#pragma unroll
    for (int r = 0; r < 4; r++)
      Ks[wv * 16 + quad * 4 + r][nj * 16 + ml] = f2b(z[r]);
  }
#pragma unroll
  for (int nj = 0; nj < 4; nj++) {
    int col = 128 + nj * 16 + ml;
    bf16x8 b0 = *(const bf16x8*)(lw + (size_t)col * 64 + quad * 8);
    bf16x8 b1 = *(const bf16x8*)(lw + (size_t)col * 64 + 32 + quad * 8);
    floatx4 z = (floatx4){0.f, 0.f, 0.f, 0.f};
    z = MFMA16(ax0, b0, z);
    z = MFMA16(ax1, b1, z);
#pragma unroll
    for (int r = 0; r < 4; r++)
      Vt[nj * 16 + ml][wv * 16 + quad * 4 + r] = f2b(z[r]);
  }
#pragma unroll
  for (int nj = 0; nj < 4; nj++) {
    int col = nj * 16 + ml;
    bf16x8 b0 = *(const bf16x8*)(lw + (size_t)col * 64 + quad * 8);
    bf16x8 b1 = *(const bf16x8*)(lw + (size_t)col * 64 + 32 + quad * 8);
    floatx4 z = (floatx4){0.f, 0.f, 0.f, 0.f};
    z = MFMA16(ax0, b0, z);
    z = MFMA16(ax1, b1, z);
#pragma unroll
    for (int r = 0; r < 4; r++)
      Ps[quad * 4 + r][nj * 16 + ml] = f2b(z[r]);
  }
  LGKM0();
  __builtin_amdgcn_sched_barrier(0);
  axq0 = *(const bf16x8*)&Ps[ml][quad * 8];
  axq1 = *(const bf16x8*)&Ps[ml][32 + quad * 8];
  LGKM0();
}

// ---------------------------------------------------------------------------
// Fused QKV-GEMM + attention: per (window, head) block computes both
// branches' q/k/v from y directly (Z eliminated: -384 MB HBM write,
// -198 MB HBM read), then window attn + head-qkv + cross attn as proven.
// XCD swizzle groups the 8 heads of a window on one XCD (y L2-reuse).
// ---------------------------------------------------------------------------
__global__ __launch_bounds__(256) void fused_qkv_attn_kernel(
    const u16* __restrict__ yW, const u16* __restrict__ yH,
    const u16* __restrict__ Wb1, const u16* __restrict__ Wb2,
    const u16* __restrict__ l3b, const u16* __restrict__ l4b,
    const float* __restrict__ pos3, const float* __restrict__ pos4,
    u16* __restrict__ o1b, u16* __restrict__ o2b) {
  // bijective swizzle: all 8 heads of window w land on XCD (w & 7), adjacent
  int id = blockIdx.x;                 // 0..8191
  int xcd = id & 7, slot = id >> 3;
  int h = slot & 7, w = (slot >> 3) * 8 + xcd;
  __shared__ u16 pool[23040];          // KsW|VtW|KsH|VtH|Ps(4 waves)
  u16 (*KsW)[72] = (u16(*)[72])pool;
  u16 (*VtW)[72] = (u16(*)[72])(pool + 4608);
  u16 (*KsH)[72] = (u16(*)[72])(pool + 9216);
  u16 (*VtH)[72] = (u16(*)[72])(pool + 13824);
  int tid = threadIdx.x, lane = tid & 63, wv = tid >> 6;
  int ml = lane & 15, quad = lane >> 4;
  u16 (*Ps)[72] = (u16(*)[72])(pool + 18432 + wv * 1152);
  // GEMM phase: both branches (wave-own output slices; no barrier needed
  // between branches -- all cross-wave-visible writes are wave-own regions)
  bf16x8 aqW0, aqW1, aqH0, aqH1;
  gemm_qkv512(yW + ((size_t)w * 64 + wv * 16) * 512, Wb1 + (size_t)h * 32768,
              KsW, VtW, Ps, wv, lane, aqW0, aqW1);
  gemm_qkv512(yH + ((size_t)w * 64 + wv * 16) * 512, Wb2 + (size_t)h * 32768,
              KsH, VtH, Ps, wv, lane, aqH0, aqH1);
  __syncthreads();                     // all k/v of both branches visible
  // per-branch window attention
  floatx4 oW[4], oH[4];
  attn_core(aqW0, aqW1, KsW, VtW, Ps, lane, oW);
  attn_core(aqH0, aqH1, KsH, VtH, Ps, lane, oH);
  __syncthreads();                     // done reading pools before overwrite
  // head-qkv: k'/v' overwrite pools, q' stays in-wave
  bf16x8 axqW0, axqW1, axqH0, axqH1;
  head_qkv(oW, pos3 + (size_t)h * 4096, l3b, KsW, VtW, Ps, wv, lane, axqW0, axqW1);
  head_qkv(oH, pos4 + (size_t)h * 4096, l4b, KsH, VtH, Ps, wv, lane, axqH0, axqH1);
  __syncthreads();                     // all k'/v' visible
  // cross attention: o2 = attn(xw_q, xh_k, xh_v); o1 = attn(xh_q, xw_k, xw_v)
  floatx4 c2[4], c1[4];
  attn_core(axqW0, axqW1, KsH, VtH, Ps, lane, c2);
  attn_core(axqH0, axqH1, KsW, VtW, Ps, lane, c1);
  __syncthreads();                     // done reading pools -> overlay Out
  u16* Out1 = pool;
  u16* Out2 = pool + 4608;
#pragma unroll
  for (int et = 0; et < 4; et++)
#pragma unroll
    for (int r = 0; r < 4; r++) {
      int row = wv * 16 + quad * 4 + r;
      Out1[row * 64 + et * 16 + ml] = f2b(c1[et][r]);
      Out2[row * 64 + et * 16 + ml] = f2b(c2[et][r]);
    }
  __syncthreads();
  u16* o1p = o1b + (size_t)w * 32768 + h * 64;
  u16* o2p = o2b + (size_t)w * 32768 + h * 64;
#pragma unroll
  for (int j = 0; j < 2; j++) {
    int c = tid + j * 256;
    int pos = c >> 3, cc = (c & 7) * 8;
    *(bf16x8*)&o1p[(size_t)pos * 512 + cc] = *(const bf16x8*)&Out1[pos * 64 + cc];
    *(bf16x8*)&o2p[(size_t)pos * 512 + cc] = *(const bf16x8*)&Out2[pos * 64 + cc];
  }
}

// ---------------------------------------------------------------------------
// Kernel E: out[token] = x[token] + o2b[token] + o1b[transposed token], fp32
// ---------------------------------------------------------------------------
__global__ __launch_bounds__(256) void final_add_kernel(
    const float* __restrict__ x, const u16* __restrict__ o1b,
    const u16* __restrict__ o2b, float* __restrict__ out) {
  int wv = threadIdx.x >> 6, lane = threadIdx.x & 63;
  int token = blockIdx.x * 4 + wv;
  int b = token >> 12, r = (token >> 6) & 63, c = token & 63;
  size_t i = (size_t)token * 512 + lane * 8;
  size_t i1 = ((size_t)b * 4096 + (size_t)c * 64 + r) * 512 + lane * 8;
  float vx[8];
  *(float4*)&vx[0] = *(const float4*)(x + i);
  *(float4*)&vx[4] = *(const float4*)(x + i + 4);
  bf16x8 v1 = *(const bf16x8*)(o1b + i1);
  bf16x8 v2 = *(const bf16x8*)(o2b + i);
  float vo[8];
#pragma unroll
  for (int j = 0; j < 8; j++)
    vo[j] = vx[j] + b2f((u16)v1[j]) + b2f((u16)v2[j]);
  *(float4*)(out + i) = *(float4*)&vo[0];
  *(float4*)(out + i + 4) = *(float4*)&vo[4];
}

extern "C" void kernel_launch(void* const* d_in, const int* in_sizes, int n_in,
                              void* d_out, int out_size, void* d_ws, size_t ws_size,
                              hipStream_t stream) {
  const float* x    = (const float*)d_in[0];
  const float* n3w  = (const float*)d_in[1];
  const float* n3b  = (const float*)d_in[2];
  const float* n4w  = (const float*)d_in[3];
  const float* n4b  = (const float*)d_in[4];
  const float* ln1  = (const float*)d_in[5];
  const float* ln2  = (const float*)d_in[6];
  const float* ln3  = (const float*)d_in[7];
  const float* ln4  = (const float*)d_in[8];
  const float* pos1 = (const float*)d_in[9];
  const float* pos2 = (const float*)d_in[10];
  const float* pos3 = (const float*)d_in[11];
  const float* pos4 = (const float*)d_in[12];

  // workspace: 256 MiB used of 512 (Z eliminated; o1b/o2b no longer alias y)
  char* ws = (char*)d_ws;
  u16* yW  = (u16*)ws;                                 //  64 MiB
  u16* yH  = (u16*)(ws + (size_t)67108864);            //  64 MiB
  u16* o1b = (u16*)(ws + (size_t)134217728);           //  64 MiB
  u16* o2b = (u16*)(ws + (size_t)201326592);           //  64 MiB
  float* out = (float*)d_out;

  // bf16 weight copies live in d_out (3 MiB of 128 MiB); final_add overwrites.
  u16* Wb1 = (u16*)d_out;            // 1536x512
  u16* Wb2 = Wb1 + 786432;
  u16* l3b = Wb2 + 786432;           // 192x64
  u16* l4b = l3b + 12288;

  cvt_all_kernel<<<1560, 256, 0, stream>>>(ln1, Wb1, ln2, Wb2, ln3, l3b, ln4, l4b);
  ln_pos_kernel<<<16384, 256, 0, stream>>>(x, n3w, n3b, n4w, n4b, pos1, pos2, yW, yH);
  fused_qkv_attn_kernel<<<8192, 256, 0, stream>>>(yW, yH, Wb1, Wb2, l3b, l4b,
                                                  pos3, pos4, o1b, o2b);
  final_add_kernel<<<16384, 256, 0, stream>>>(x, o1b, o2b, out);
}

// Round 14
// 821.078 us; speedup vs baseline: 2.4814x; 2.4814x over previous
//
#include <hip/hip_runtime.h>
#include <hip/hip_bf16.h>

typedef unsigned short u16;
typedef __attribute__((ext_vector_type(8))) short bf16x8;
typedef __attribute__((ext_vector_type(4))) short bf16x4;
typedef __attribute__((ext_vector_type(4))) float floatx4;
typedef __attribute__((ext_vector_type(4))) unsigned short u16x4;

__device__ __forceinline__ float b2f(u16 u) {
  unsigned int i = ((unsigned int)u) << 16;
  return __builtin_bit_cast(float, i);
}
__device__ __forceinline__ u16 f2b(float f) {
  __hip_bfloat16 h = __float2bfloat16(f);
  return __builtin_bit_cast(u16, h);
}
#define MFMA16(a, b, c) __builtin_amdgcn_mfma_f32_16x16x32_bf16((a), (b), (c), 0, 0, 0)
#define LGKM0() __asm__ volatile("s_waitcnt lgkmcnt(0)" ::: "memory")
#define VM0() __asm__ volatile("s_waitcnt vmcnt(0)" ::: "memory")
#define BAR() do { __asm__ volatile("" ::: "memory"); \
  __builtin_amdgcn_s_barrier(); \
  __asm__ volatile("" ::: "memory"); } while (0)

#if __has_builtin(__builtin_amdgcn_mfma_f32_16x16x16bf16_1k)
#define HAVE_MFMA_K16 1
#define MFMA16K16(a, b, c) __builtin_amdgcn_mfma_f32_16x16x16bf16_1k((a), (b), (c), 0, 0, 0)
#else
#define HAVE_MFMA_K16 0
#endif

__device__ __forceinline__ void gload_lds16(const u16* g, u16* l) {
  __builtin_amdgcn_global_load_lds(
      (const __attribute__((address_space(1))) void*)g,
      (__attribute__((address_space(3))) void*)l, 16, 0, 0);
}

// ---------------------------------------------------------------------------
// Kernel 0: fp32 -> bf16 conversion of ALL FOUR weight arrays in ONE launch.
// ---------------------------------------------------------------------------
__global__ __launch_bounds__(256) void cvt_all_kernel(
    const float* __restrict__ a1, u16* __restrict__ o1,
    const float* __restrict__ a2, u16* __restrict__ o2,
    const float* __restrict__ a3, u16* __restrict__ o3,
    const float* __restrict__ a4, u16* __restrict__ o4) {
  int b = blockIdx.x;
  const float* a; u16* o; int i; int n4;
  if (b < 768)       { a = a1; o = o1; i = b * 256 + threadIdx.x;          n4 = 196608; }
  else if (b < 1536) { a = a2; o = o2; i = (b - 768) * 256 + threadIdx.x;  n4 = 196608; }
  else if (b < 1548) { a = a3; o = o3; i = (b - 1536) * 256 + threadIdx.x; n4 = 3072; }
  else               { a = a4; o = o4; i = (b - 1548) * 256 + threadIdx.x; n4 = 3072; }
  if (i < n4) {
    float4 v = ((const float4*)a)[i];
    u16x4 r;
    r.x = f2b(v.x); r.y = f2b(v.y); r.z = f2b(v.z); r.w = f2b(v.w);
    ((u16x4*)o)[i] = r;
  }
}

// ---------------------------------------------------------------------------
// Kernel A: LayerNorm (shared mu/rsigma) + pos add -> both branch layouts, bf16
// ---------------------------------------------------------------------------
__global__ __launch_bounds__(256) void ln_pos_kernel(
    const float* __restrict__ x, const float* __restrict__ n3w, const float* __restrict__ n3b,
    const float* __restrict__ n4w, const float* __restrict__ n4b,
    const float* __restrict__ pos1, const float* __restrict__ pos2,
    u16* __restrict__ yW, u16* __restrict__ yH) {
  int wv = threadIdx.x >> 6, lane = threadIdx.x & 63;
  int token = blockIdx.x * 4 + wv;
  int b = token >> 12, r = (token >> 6) & 63, c = token & 63;
  const float4* xr = (const float4*)(x + (size_t)token * 512) + lane * 2;
  float4 x0 = xr[0], x1 = xr[1];
  float v[8] = {x0.x, x0.y, x0.z, x0.w, x1.x, x1.y, x1.z, x1.w};
  float s = 0.f, ss = 0.f;
#pragma unroll
  for (int j = 0; j < 8; j++) { s += v[j]; ss += v[j] * v[j]; }
#pragma unroll
  for (int off = 1; off < 64; off <<= 1) { s += __shfl_xor(s, off); ss += __shfl_xor(ss, off); }
  float mu = s * (1.0f / 512.0f);
  float var = ss * (1.0f / 512.0f) - mu * mu;
  float rs = rsqrtf(var + 1e-5f);
  int ch0 = lane * 8;
  float w3[8], b3[8], w4[8], b4[8], p1[8], p2[8];
  *(float4*)&w3[0] = *(const float4*)(n3w + ch0); *(float4*)&w3[4] = *(const float4*)(n3w + ch0 + 4);
  *(float4*)&b3[0] = *(const float4*)(n3b + ch0); *(float4*)&b3[4] = *(const float4*)(n3b + ch0 + 4);
  *(float4*)&w4[0] = *(const float4*)(n4w + ch0); *(float4*)&w4[4] = *(const float4*)(n4w + ch0 + 4);
  *(float4*)&b4[0] = *(const float4*)(n4b + ch0); *(float4*)&b4[4] = *(const float4*)(n4b + ch0 + 4);
  const float* p1p = pos1 + (size_t)c * 512 + ch0;
  const float* p2p = pos2 + (size_t)r * 512 + ch0;
  *(float4*)&p1[0] = *(const float4*)p1p; *(float4*)&p1[4] = *(const float4*)(p1p + 4);
  *(float4*)&p2[0] = *(const float4*)p2p; *(float4*)&p2[4] = *(const float4*)(p2p + 4);
  bf16x8 ow, oh;
#pragma unroll
  for (int j = 0; j < 8; j++) {
    float xn = (v[j] - mu) * rs;
    ow[j] = (short)f2b(xn * w3[j] + b3[j] + p1[j]);
    oh[j] = (short)f2b(xn * w4[j] + b4[j] + p2[j]);
  }
  *(bf16x8*)(yW + (size_t)token * 512 + ch0) = ow;
  size_t hrow = (size_t)b * 4096 + (size_t)c * 64 + r;
  *(bf16x8*)(yH + hrow * 512 + ch0) = oh;
}

// ---------------------------------------------------------------------------
// Kernel B: QKV GEMM, 256x256 tile, 8-wave (2Mx4N), BK=64, 8-phase schedule,
// counted vmcnt(6), T2 swizzle via pre-swizzled global source. (round-9 WIN)
// ---------------------------------------------------------------------------
__global__ __launch_bounds__(512, 1) void qkv_gemm_kernel(
    const u16* __restrict__ A0, const u16* __restrict__ A1,
    const u16* __restrict__ W0, const u16* __restrict__ W1,
    u16* __restrict__ Z0, u16* __restrict__ Z1) {
  const int K = 512, N = 1536, NT = 8;
  extern __shared__ u16 lds[];               // A0|A1|B0|B1, 16384 u16 each
  int br = blockIdx.z;
  const u16* A = br ? A1 : A0;
  const u16* W = br ? W1 : W0;
  u16* Z = br ? Z1 : Z0;
  int lin = blockIdx.y * 6 + blockIdx.x;     // 1536 blocks per branch
  int nl = (lin & 7) * 192 + (lin >> 3);     // bijective XCD chunking (1536%8==0)
  int m0 = (nl / 6) * 256, n0 = (nl % 6) * 256;
  int tid = threadIdx.x, lane = tid & 63, wv = tid >> 6;
  int wm = wv >> 2, wn = wv & 3;
  int ml = lane & 15, quad = lane >> 4;
  int l8 = lane >> 3;
  int scol = ((lane & 7) ^ l8) << 3;

  floatx4 acc[8][4];
#pragma unroll
  for (int mi = 0; mi < 8; mi++)
#pragma unroll
    for (int n = 0; n < 4; n++) acc[mi][n] = (floatx4){0.f, 0.f, 0.f, 0.f};

  auto stA = [&](int kt, int ab, int q) {
    int row = (wv < 4) ? (q * 32 + wv * 8) : (128 + q * 32 + (wv - 4) * 8);
    gload_lds16(A + (size_t)(m0 + row + l8) * K + kt + scol,
                &lds[ab * 16384 + row * 64]);
  };
  auto stB = [&](int kt, int bb, int q) {
    int row = q * 64 + wv * 8;
    gload_lds16(W + (size_t)(n0 + row + l8) * K + kt + scol,
                &lds[32768 + bb * 16384 + row * 64]);
  };
  auto rdA = [&](int ab, int row, int sl) {
    return *(const bf16x8*)&lds[ab * 16384 + row * 64 + (((sl ^ (row & 7)) & 7) << 3)];
  };
  auto rdB = [&](int bb, int row, int sl) {
    return *(const bf16x8*)&lds[32768 + bb * 16384 + row * 64 + (((sl ^ (row & 7)) & 7) << 3)];
  };

#pragma unroll
  for (int q = 0; q < 4; q++) { stA(0, 0, q); stB(0, 0, q); }
#pragma unroll
  for (int q = 0; q < 3; q++) { stA(64, 1, q); stB(64, 1, q); }
  __asm__ volatile("s_waitcnt vmcnt(6)" ::: "memory");
  BAR();

  for (int t = 0; t < NT; ++t) {
    int b = t & 1;
    bf16x8 bfr[4][2];
    {
      bf16x8 af[2][2];
#pragma unroll
      for (int n = 0; n < 4; n++)
#pragma unroll
        for (int kh = 0; kh < 2; kh++)
          bfr[n][kh] = rdB(b, wn * 64 + n * 16 + ml, kh * 4 + quad);
#pragma unroll
      for (int mh = 0; mh < 2; mh++)
#pragma unroll
        for (int kh = 0; kh < 2; kh++)
          af[mh][kh] = rdA(b, wm * 128 + mh * 16 + ml, kh * 4 + quad);
      if (t + 1 < NT) { stA((t + 1) * 64, (t + 1) & 1, 3); stB((t + 1) * 64, (t + 1) & 1, 3); }
      BAR();
      __builtin_amdgcn_s_setprio(1);
#pragma unroll
      for (int mh = 0; mh < 2; mh++)
#pragma unroll
        for (int n = 0; n < 4; n++) {
          acc[mh][n] = MFMA16(af[mh][0], bfr[n][0], acc[mh][n]);
          acc[mh][n] = MFMA16(af[mh][1], bfr[n][1], acc[mh][n]);
        }
      __builtin_amdgcn_s_setprio(0);
      BAR();
    }
#pragma unroll
    for (int p = 1; p < 4; p++) {
      bf16x8 af[2][2];
#pragma unroll
      for (int mh = 0; mh < 2; mh++)
#pragma unroll
        for (int kh = 0; kh < 2; kh++)
          af[mh][kh] = rdA(b, wm * 128 + (p * 2 + mh) * 16 + ml, kh * 4 + quad);
      if (t + 2 < NT) { stA((t + 2) * 64, b, p - 1); stB((t + 2) * 64, b, p - 1); }
      BAR();
      __builtin_amdgcn_s_setprio(1);
#pragma unroll
      for (int mh = 0; mh < 2; mh++)
#pragma unroll
        for (int n = 0; n < 4; n++) {
          acc[p * 2 + mh][n] = MFMA16(af[mh][0], bfr[n][0], acc[p * 2 + mh][n]);
          acc[p * 2 + mh][n] = MFMA16(af[mh][1], bfr[n][1], acc[p * 2 + mh][n]);
        }
      __builtin_amdgcn_s_setprio(0);
      if (p < 3) BAR();
    }
    if (t + 2 < NT) { __asm__ volatile("s_waitcnt vmcnt(6)" ::: "memory"); }
    else            { __asm__ volatile("s_waitcnt vmcnt(0)" ::: "memory"); }
    BAR();
  }

  u16* wl = lds + wv * 2048;
#pragma unroll
  for (int mp = 0; mp < 4; mp++) {
#pragma unroll
    for (int mh = 0; mh < 2; mh++) {
      int mi = mp * 2 + mh;
#pragma unroll
      for (int n = 0; n < 4; n++)
#pragma unroll
        for (int r = 0; r < 4; r++)
          wl[(mh * 16 + quad * 4 + r) * 64 + n * 16 + ml] = f2b(acc[mi][n][r]);
    }
    LGKM0();
#pragma unroll
    for (int p2 = 0; p2 < 4; p2++) {
      int lrow = p2 * 8 + (lane >> 3);
      int col8 = (lane & 7) * 8;
      bf16x8 vv = *(const bf16x8*)&wl[lrow * 64 + col8];
      int rg = m0 + wm * 128 + mp * 32 + lrow;
      *(bf16x8*)&Z[(size_t)rg * N + n0 + wn * 64 + col8] = vv;
    }
    LGKM0();
  }
}

// ---------------------------------------------------------------------------
// Shared attention core, SWAPPED layout (round-6/8 proven): S^T = mfma(K, Q);
// softmax: max over RAW scores, exp via fma(s,0.125,-m*0.125); PV via 16
// K=16 MFMAs straight from registers.
// ---------------------------------------------------------------------------
__device__ __forceinline__ void attn_core(bf16x8 aq0, bf16x8 aq1,
                                          const u16 (*Ks)[72], const u16 (*Vt)[72],
                                          u16 (*Psw)[72], int lane, floatx4 o[4]) {
  int ml = lane & 15, quad = lane >> 4;
  floatx4 s[4];
#pragma unroll
  for (int nt = 0; nt < 4; nt++) {
    floatx4 z = (floatx4){0.f, 0.f, 0.f, 0.f};
    bf16x8 k0 = *(const bf16x8*)&Ks[nt * 16 + ml][quad * 8];
    bf16x8 k1 = *(const bf16x8*)&Ks[nt * 16 + ml][32 + quad * 8];
    z = MFMA16(k0, aq0, z);          // swapped operands: D = S^T
    z = MFMA16(k1, aq1, z);
    s[nt] = z;
  }
  float m = -1e30f;
#pragma unroll
  for (int nt = 0; nt < 4; nt++)
#pragma unroll
    for (int r = 0; r < 4; r++) m = fmaxf(m, s[nt][r]);
  m = fmaxf(m, __shfl_xor(m, 16));
  m = fmaxf(m, __shfl_xor(m, 32));
  float mh = -m * 0.125f;
  float su = 0.f;
#pragma unroll
  for (int nt = 0; nt < 4; nt++)
#pragma unroll
    for (int r = 0; r < 4; r++) {
      float p = __expf(__builtin_fmaf(s[nt][r], 0.125f, mh));
      s[nt][r] = p; su += p;
    }
  su += __shfl_xor(su, 16);
  su += __shfl_xor(su, 32);
  float inv = 1.0f / su;
#if HAVE_MFMA_K16
  bf16x4 pa[4];
#pragma unroll
  for (int nt = 0; nt < 4; nt++)
#pragma unroll
    for (int r = 0; r < 4; r++) pa[nt][r] = (short)f2b(s[nt][r] * inv);
#pragma unroll
  for (int et = 0; et < 4; et++) {
    floatx4 z = (floatx4){0.f, 0.f, 0.f, 0.f};
#pragma unroll
    for (int nt = 0; nt < 4; nt++) {
      bf16x4 bv = *(const bf16x4*)&Vt[et * 16 + ml][nt * 16 + quad * 4];
      z = MFMA16K16(pa[nt], bv, z);
    }
    o[et] = z;
  }
#else
#pragma unroll
  for (int nt = 0; nt < 4; nt++)
#pragma unroll
    for (int r = 0; r < 4; r++)
      Psw[ml][nt * 16 + quad * 4 + r] = f2b(s[nt][r] * inv);
  LGKM0();
  bf16x8 ap0 = *(const bf16x8*)&Psw[ml][quad * 8];
  bf16x8 ap1 = *(const bf16x8*)&Psw[ml][32 + quad * 8];
#pragma unroll
  for (int et = 0; et < 4; et++) {
    floatx4 z = (floatx4){0.f, 0.f, 0.f, 0.f};
    bf16x8 b0 = *(const bf16x8*)&Vt[et * 16 + ml][quad * 8];
    bf16x8 b1 = *(const bf16x8*)&Vt[et * 16 + ml][32 + quad * 8];
    z = MFMA16(ap0, b0, z);
    z = MFMA16(ap1, b1, z);
    o[et] = z;
  }
#endif
}

// ---------------------------------------------------------------------------
// head-QKV (proven): x = o + pos via per-wave Ps round-trip, then
// x @ lw^T (64x192): k' -> Ks rows, v' -> Vt cols, q' -> Ps round-trip.
// ---------------------------------------------------------------------------
__device__ __forceinline__ void head_qkv(const floatx4 o[4], const float* pp,
                                         const u16* lw, u16 (*Ks)[72], u16 (*Vt)[72],
                                         u16 (*Ps)[72], int wv, int lane,
                                         bf16x8& axq0, bf16x8& axq1) {
  int ml = lane & 15, quad = lane >> 4;
#pragma unroll
  for (int et = 0; et < 4; et++)
#pragma unroll
    for (int r = 0; r < 4; r++) {
      int qp = wv * 16 + quad * 4 + r, e = et * 16 + ml;
      Ps[quad * 4 + r][et * 16 + ml] = f2b(o[et][r] + pp[(size_t)qp * 64 + e]);
    }
  LGKM0();
  bf16x8 ax0 = *(const bf16x8*)&Ps[ml][quad * 8];
  bf16x8 ax1 = *(const bf16x8*)&Ps[ml][32 + quad * 8];
  LGKM0();
  __builtin_amdgcn_sched_barrier(0);
#pragma unroll
  for (int nj = 0; nj < 4; nj++) {
    int col = 64 + nj * 16 + ml;
    bf16x8 b0 = *(const bf16x8*)(lw + (size_t)col * 64 + quad * 8);
    bf16x8 b1 = *(const bf16x8*)(lw + (size_t)col * 64 + 32 + quad * 8);
    floatx4 z = (floatx4){0.f, 0.f, 0.f, 0.f};
    z = MFMA16(ax0, b0, z);
    z = MFMA16(ax1, b1, z);
#pragma unroll
    for (int r = 0; r < 4; r++)
      Ks[wv * 16 + quad * 4 + r][nj * 16 + ml] = f2b(z[r]);
  }
#pragma unroll
  for (int nj = 0; nj < 4; nj++) {
    int col = 128 + nj * 16 + ml;
    bf16x8 b0 = *(const bf16x8*)(lw + (size_t)col * 64 + quad * 8);
    bf16x8 b1 = *(const bf16x8*)(lw + (size_t)col * 64 + 32 + quad * 8);
    floatx4 z = (floatx4){0.f, 0.f, 0.f, 0.f};
    z = MFMA16(ax0, b0, z);
    z = MFMA16(ax1, b1, z);
#pragma unroll
    for (int r = 0; r < 4; r++)
      Vt[nj * 16 + ml][wv * 16 + quad * 4 + r] = f2b(z[r]);
  }
#pragma unroll
  for (int nj = 0; nj < 4; nj++) {
    int col = nj * 16 + ml;
    bf16x8 b0 = *(const bf16x8*)(lw + (size_t)col * 64 + quad * 8);
    bf16x8 b1 = *(const bf16x8*)(lw + (size_t)col * 64 + 32 + quad * 8);
    floatx4 z = (floatx4){0.f, 0.f, 0.f, 0.f};
    z = MFMA16(ax0, b0, z);
    z = MFMA16(ax1, b1, z);
#pragma unroll
    for (int r = 0; r < 4; r++)
      Ps[quad * 4 + r][nj * 16 + ml] = f2b(z[r]);
  }
  LGKM0();
  __builtin_amdgcn_sched_barrier(0);
  axq0 = *(const bf16x8*)&Ps[ml][quad * 8];
  axq1 = *(const bf16x8*)&Ps[ml][32 + quad * 8];
  LGKM0();
}

// ---------------------------------------------------------------------------
// Kernel C+D fused (round-6/8/9 proven structure)
// ---------------------------------------------------------------------------
__global__ __launch_bounds__(256) void fused_attn_kernel(
    const u16* __restrict__ Zw, const u16* __restrict__ Zh,
    const u16* __restrict__ l3b, const u16* __restrict__ l4b,
    const float* __restrict__ pos3, const float* __restrict__ pos4,
    u16* __restrict__ o1b, u16* __restrict__ o2b) {
  int w = blockIdx.x, h = blockIdx.y;
  __shared__ u16 pool[23040];                 // KsW|VtW|KsH|VtH|Ps(4 waves)
  u16 (*KsW)[72] = (u16(*)[72])pool;
  u16 (*VtW)[72] = (u16(*)[72])(pool + 4608);
  u16 (*KsH)[72] = (u16(*)[72])(pool + 9216);
  u16 (*VtH)[72] = (u16(*)[72])(pool + 13824);
  int tid = threadIdx.x, lane = tid & 63, wv = tid >> 6;
  int ml = lane & 15, quad = lane >> 4;
  u16 (*Ps)[72] = (u16(*)[72])(pool + 18432 + wv * 1152);
  const u16* baseW = Zw + (size_t)w * 64 * 1536 + h * 64;
  const u16* baseH = Zh + (size_t)w * 64 * 1536 + h * 64;
  for (int i = tid; i < 512; i += 256) {
    int r = i >> 3, c = (i & 7) * 8;
    *(bf16x8*)&KsW[r][c] = *(const bf16x8*)(baseW + 512 + (size_t)r * 1536 + c);
    *(bf16x8*)&KsH[r][c] = *(const bf16x8*)(baseH + 512 + (size_t)r * 1536 + c);
  }
  for (int i = tid; i < 1024; i += 256) {
    int p = i >> 4, e0 = (i & 15) * 4;
    u16x4 vW = *(const u16x4*)(baseW + 1024 + (size_t)p * 1536 + e0);
    u16x4 vH = *(const u16x4*)(baseH + 1024 + (size_t)p * 1536 + e0);
    VtW[e0 + 0][p] = vW.x; VtW[e0 + 1][p] = vW.y; VtW[e0 + 2][p] = vW.z; VtW[e0 + 3][p] = vW.w;
    VtH[e0 + 0][p] = vH.x; VtH[e0 + 1][p] = vH.y; VtH[e0 + 2][p] = vH.z; VtH[e0 + 3][p] = vH.w;
  }
  const u16* qrW = baseW + (size_t)(wv * 16 + ml) * 1536 + quad * 8;
  const u16* qrH = baseH + (size_t)(wv * 16 + ml) * 1536 + quad * 8;
  bf16x8 aqW0 = *(const bf16x8*)qrW;
  bf16x8 aqW1 = *(const bf16x8*)(qrW + 32);
  bf16x8 aqH0 = *(const bf16x8*)qrH;
  bf16x8 aqH1 = *(const bf16x8*)(qrH + 32);
  __syncthreads();
  floatx4 oW[4], oH[4];
  attn_core(aqW0, aqW1, KsW, VtW, Ps, lane, oW);
  attn_core(aqH0, aqH1, KsH, VtH, Ps, lane, oH);
  __syncthreads();
  bf16x8 axqW0, axqW1, axqH0, axqH1;
  head_qkv(oW, pos3 + (size_t)h * 4096, l3b, KsW, VtW, Ps, wv, lane, axqW0, axqW1);
  __syncthreads();
  head_qkv(oH, pos4 + (size_t)h * 4096, l4b, KsH, VtH, Ps, wv, lane, axqH0, axqH1);
  __syncthreads();
  floatx4 c2[4], c1[4];
  attn_core(axqW0, axqW1, KsH, VtH, Ps, lane, c2);
  attn_core(axqH0, axqH1, KsW, VtW, Ps, lane, c1);
  __syncthreads();
  u16* Out1 = pool;
  u16* Out2 = pool + 4608;
#pragma unroll
  for (int et = 0; et < 4; et++)
#pragma unroll
    for (int r = 0; r < 4; r++) {
      int row = wv * 16 + quad * 4 + r;
      Out1[row * 64 + et * 16 + ml] = f2b(c1[et][r]);
      Out2[row * 64 + et * 16 + ml] = f2b(c2[et][r]);
    }
  __syncthreads();
  u16* o1p = o1b + (size_t)w * 32768 + h * 64;
  u16* o2p = o2b + (size_t)w * 32768 + h * 64;
#pragma unroll
  for (int j = 0; j < 2; j++) {
    int c = tid + j * 256;
    int pos = c >> 3, cc = (c & 7) * 8;
    *(bf16x8*)&o1p[(size_t)pos * 512 + cc] = *(const bf16x8*)&Out1[pos * 64 + cc];
    *(bf16x8*)&o2p[(size_t)pos * 512 + cc] = *(const bf16x8*)&Out2[pos * 64 + cc];
  }
}

// ---------------------------------------------------------------------------
// Kernel E: out[token] = x[token] + o2b[token] + o1b[transposed token], fp32
// ---------------------------------------------------------------------------
__global__ __launch_bounds__(256) void final_add_kernel(
    const float* __restrict__ x, const u16* __restrict__ o1b,
    const u16* __restrict__ o2b, float* __restrict__ out) {
  int wv = threadIdx.x >> 6, lane = threadIdx.x & 63;
  int token = blockIdx.x * 4 + wv;
  int b = token >> 12, r = (token >> 6) & 63, c = token & 63;
  size_t i = (size_t)token * 512 + lane * 8;
  size_t i1 = ((size_t)b * 4096 + (size_t)c * 64 + r) * 512 + lane * 8;
  float vx[8];
  *(float4*)&vx[0] = *(const float4*)(x + i);
  *(float4*)&vx[4] = *(const float4*)(x + i + 4);
  bf16x8 v1 = *(const bf16x8*)(o1b + i1);
  bf16x8 v2 = *(const bf16x8*)(o2b + i);
  float vo[8];
#pragma unroll
  for (int j = 0; j < 8; j++)
    vo[j] = vx[j] + b2f((u16)v1[j]) + b2f((u16)v2[j]);
  *(float4*)(out + i) = *(float4*)&vo[0];
  *(float4*)(out + i + 4) = *(float4*)&vo[4];
}

extern "C" void kernel_launch(void* const* d_in, const int* in_sizes, int n_in,
                              void* d_out, int out_size, void* d_ws, size_t ws_size,
                              hipStream_t stream) {
  const float* x    = (const float*)d_in[0];
  const float* n3w  = (const float*)d_in[1];
  const float* n3b  = (const float*)d_in[2];
  const float* n4w  = (const float*)d_in[3];
  const float* n4b  = (const float*)d_in[4];
  const float* ln1  = (const float*)d_in[5];
  const float* ln2  = (const float*)d_in[6];
  const float* ln3  = (const float*)d_in[7];
  const float* ln4  = (const float*)d_in[8];
  const float* pos1 = (const float*)d_in[9];
  const float* pos2 = (const float*)d_in[10];
  const float* pos3 = (const float*)d_in[11];
  const float* pos4 = (const float*)d_in[12];

  // workspace: exactly 512 MiB (proven-safe footprint)
  char* ws = (char*)d_ws;
  u16* yW = (u16*)ws;                                  //  64 MiB (65536x512 bf16)
  u16* yH = (u16*)(ws + (size_t)67108864);             //  64 MiB
  u16* Zw = (u16*)(ws + (size_t)134217728);            // 192 MiB (65536x1536 bf16)
  u16* Zh = (u16*)(ws + (size_t)335544320);            // 192 MiB  (end = 512 MiB)
  u16* o1b = yW;                                       // alias: y consumed by GEMM
  u16* o2b = yH;
  float* out = (float*)d_out;

  // bf16 weight copies live in d_out (3 MiB of 128 MiB); final_add overwrites.
  u16* Wb1 = (u16*)d_out;            // 1536x512
  u16* Wb2 = Wb1 + 786432;
  u16* l3b = Wb2 + 786432;           // 192x64
  u16* l4b = l3b + 12288;

  // allow 128 KiB dynamic LDS for the GEMM (no-op if already permitted)
  static bool lds_attr_set = false;
  if (!lds_attr_set) {
    hipFuncSetAttribute((const void*)qkv_gemm_kernel,
                        hipFuncAttributeMaxDynamicSharedMemorySize, 131072);
    lds_attr_set = true;
  }

  cvt_all_kernel<<<1560, 256, 0, stream>>>(ln1, Wb1, ln2, Wb2, ln3, l3b, ln4, l4b);
  ln_pos_kernel<<<16384, 256, 0, stream>>>(x, n3w, n3b, n4w, n4b, pos1, pos2, yW, yH);
  qkv_gemm_kernel<<<dim3(6, 256, 2), 512, 131072, stream>>>(yW, yH, Wb1, Wb2, Zw, Zh);
  fused_attn_kernel<<<dim3(1024, 8), 256, 0, stream>>>(Zw, Zh, l3b, l4b, pos3, pos4, o1b, o2b);
  final_add_kernel<<<16384, 256, 0, stream>>>(x, o1b, o2b, out);
}